// Round 1
// baseline (362.161 us; speedup 1.0000x reference)
//
#include <hip/hip_runtime.h>
#include <cstdint>
#include <cstddef>

// LLAConv2d: per-sample 1x1 conv == 32 independent GEMMs
//   out[b,o,p] = sum_i K[b,o,i] * x[b,i,p],  K[b] = sum_e alpha[b,e]*ke[e]
// B=32, Cin=Cout=64, P=160*160=25600. fp32 in/out.
// Memory-bound: 420 MB HBM traffic -> ~67us floor @6.3TB/s. fp32 VALU compute
// floor 43us (no fp32 MFMA on CDNA4) -> hide compute under HBM.

#define PIX 25600
#define CIN 64
#define COUT 64
#define BATCH 32
#define NEXP 8
#define TILE_PX 256
#define TILES_PER_B (PIX / TILE_PX) // 100

__device__ __forceinline__ void load_lds16(const float* g, float* l) {
  // async global->LDS, 16B per lane; LDS dst = wave-uniform base + lane*16
  __builtin_amdgcn_global_load_lds(
      (__attribute__((address_space(1))) void*)(g),
      (__attribute__((address_space(3))) void*)(l), 16, 0, 0);
}

// ---------------- Kernel A: mix kernels, store TRANSPOSED kt[b][i][o] -------
// 256 blocks x 256 threads; block handles 512 entries of one sample.
__global__ __launch_bounds__(256) void mix_kernel(
    const float* __restrict__ alpha, const float* __restrict__ ke,
    float* __restrict__ kt) {
  const int b = blockIdx.x >> 3;
  const int seg = blockIdx.x & 7;
  __shared__ float a[NEXP];
  if (threadIdx.x < NEXP) a[threadIdx.x] = alpha[b * NEXP + threadIdx.x];
  __syncthreads();
#pragma unroll
  for (int t = 0; t < 2; t++) {
    const int idx = seg * 512 + t * 256 + threadIdx.x; // idx = o*64 + i
    float s = 0.f;
#pragma unroll
    for (int e = 0; e < NEXP; e++) s += a[e] * ke[e * 4096 + idx];
    const int o = idx >> 6, i = idx & 63;
    kt[b * 4096 + i * 64 + o] = s; // transposed: [i][o]
  }
}

// ---------------- Kernel B: the 1x1-conv GEMM --------------------------------
// Block = (sample b) x (256-pixel tile). 256 threads.
// Thread tile: 8 out-channels x 8 pixels (64 acc regs).
//   tc = tid>>5 (8 channel groups), tp = tid&31 (32 pixel groups of 8).
// LDS: ks[64][64] (16KB, [i][o]) + xs[32 rows][256 px] (32KB, granule-swizzled)
//   -> 48KB/block -> 3 blocks/CU.
// xs swizzle: 16B granule g stored at slot g^((g>>3)&7) (involution). Readers
// (granules 2tp, 2tp+1) then hit all 8 bank-groups exactly once -> no conflict.
__global__ __launch_bounds__(256, 3) void conv_kernel(
    const float* __restrict__ x, const float* __restrict__ kt,
    float* __restrict__ out) {
  __shared__ float ks[CIN * COUT];
  __shared__ float xs[32 * TILE_PX];

  const int bid = blockIdx.x;
  const int b = bid / TILES_PER_B;
  const int tile = bid - b * TILES_PER_B;
  const int P0 = tile * TILE_PX;

  const int tid = threadIdx.x;
  const int wave = tid >> 6;
  const int lane = tid & 63;
  const int tc = tid >> 5; // 0..7
  const int tp = tid & 31; // 0..31

  const float* xb = x + (size_t)b * CIN * PIX + P0;
  const float* kb = kt + b * 4096;

  // Stage ks (identity layout): 16 rows of 256 floats, wave w does rows 4w..4w+3
#pragma unroll
  for (int j = 0; j < 4; j++) {
    const int row = wave * 4 + j;
    load_lds16(kb + row * 256 + lane * 4, &ks[row * 256]);
  }

  const int swzl = lane ^ ((lane >> 3) & 7); // global granule this lane fetches

  // Stage xs chunk 0 (input rows i=0..31): wave w stages rows 8w..8w+7
#pragma unroll
  for (int j = 0; j < 8; j++) {
    const int i = wave * 8 + j;
    load_lds16(xb + (size_t)i * PIX + swzl * 4, &xs[i * TILE_PX]);
  }

  float acc[8][8];
#pragma unroll
  for (int c = 0; c < 8; c++)
#pragma unroll
    for (int p = 0; p < 8; p++) acc[c][p] = 0.f;

  const int g0 = 2 * tp, g1 = 2 * tp + 1;
  const int off0 = (g0 ^ ((g0 >> 3) & 7)) * 16; // byte offset within xs row
  const int off1 = (g1 ^ ((g1 >> 3) & 7)) * 16;
  const char* xsb = (const char*)xs;
  const int kcol = tc * 8;

  __syncthreads(); // drains vmcnt(0): staged data visible

  // ---- chunk 0: input rows 0..31 ----
#pragma unroll 2
  for (int ii = 0; ii < 32; ii++) {
    const float4 xv0 = *(const float4*)(xsb + ii * (TILE_PX * 4) + off0);
    const float4 xv1 = *(const float4*)(xsb + ii * (TILE_PX * 4) + off1);
    const float4 k0 = *(const float4*)&ks[ii * 64 + kcol];
    const float4 k1 = *(const float4*)&ks[ii * 64 + kcol + 4];
    const float kc[8] = {k0.x, k0.y, k0.z, k0.w, k1.x, k1.y, k1.z, k1.w};
    const float xp[8] = {xv0.x, xv0.y, xv0.z, xv0.w, xv1.x, xv1.y, xv1.z, xv1.w};
#pragma unroll
    for (int c = 0; c < 8; c++)
#pragma unroll
      for (int p = 0; p < 8; p++) acc[c][p] = fmaf(kc[c], xp[p], acc[c][p]);
  }

  __syncthreads(); // all reads of chunk 0 done before overwrite

  // Stage xs chunk 1 (input rows i=32..63)
#pragma unroll
  for (int j = 0; j < 8; j++) {
    const int i = 32 + wave * 8 + j;
    load_lds16(xb + (size_t)i * PIX + swzl * 4, &xs[(i - 32) * TILE_PX]);
  }

  __syncthreads();

  // ---- chunk 1: input rows 32..63 ----
#pragma unroll 2
  for (int ii = 0; ii < 32; ii++) {
    const float4 xv0 = *(const float4*)(xsb + ii * (TILE_PX * 4) + off0);
    const float4 xv1 = *(const float4*)(xsb + ii * (TILE_PX * 4) + off1);
    const float4 k0 = *(const float4*)&ks[(32 + ii) * 64 + kcol];
    const float4 k1 = *(const float4*)&ks[(32 + ii) * 64 + kcol + 4];
    const float kc[8] = {k0.x, k0.y, k0.z, k0.w, k1.x, k1.y, k1.z, k1.w};
    const float xp[8] = {xv0.x, xv0.y, xv0.z, xv0.w, xv1.x, xv1.y, xv1.z, xv1.w};
#pragma unroll
    for (int c = 0; c < 8; c++)
#pragma unroll
      for (int p = 0; p < 8; p++) acc[c][p] = fmaf(kc[c], xp[p], acc[c][p]);
  }

  // ---- epilogue: 8 channels x 2 float4 stores, coalesced per tc-half ----
  float* ob = out + ((size_t)(b * COUT + tc * 8)) * PIX + P0 + tp * 8;
#pragma unroll
  for (int c = 0; c < 8; c++) {
    *(float4*)(ob + (size_t)c * PIX) =
        make_float4(acc[c][0], acc[c][1], acc[c][2], acc[c][3]);
    *(float4*)(ob + (size_t)c * PIX + 4) =
        make_float4(acc[c][4], acc[c][5], acc[c][6], acc[c][7]);
  }
}

extern "C" void kernel_launch(void* const* d_in, const int* in_sizes, int n_in,
                              void* d_out, int out_size, void* d_ws,
                              size_t ws_size, hipStream_t stream) {
  const float* x = (const float*)d_in[0];     // [32,64,160,160]
  const float* alpha = (const float*)d_in[1]; // [32,8]
  const float* ke = (const float*)d_in[2];    // [8,64,64,1,1]
  float* out = (float*)d_out;                 // [32,64,160,160]
  float* kt = (float*)d_ws;                   // 32*4096 floats = 512KB scratch

  mix_kernel<<<BATCH * 8, 256, 0, stream>>>(alpha, ke, kt);
  conv_kernel<<<BATCH * TILES_PER_B, 256, 0, stream>>>(x, kt, out);
}

// Round 2
// 353.766 us; speedup vs baseline: 1.0237x; 1.0237x over previous
//
#include <hip/hip_runtime.h>
#include <cstdint>
#include <cstddef>

// LLAConv2d: per-sample 1x1 conv == 32 independent GEMMs
//   out[b,o,p] = sum_i K[b,o,i] * x[b,i,p],  K[b] = sum_e alpha[b,e]*ke[e]
// B=32, Cin=Cout=64, P=160*160=25600, fp32.
// Floors: HBM ~50-66us (316-420MB @6.3TB/s, L3 absorbs part of fetch),
//         fp32 VALU ~43us pure-FMA (no fp32 MFMA on CDNA4).
// R1 (132us) was stall-bound: 3 barriers/block, no overlap. R2: single-stage
// block (one barrier), full-K tile, conflict-free consecutive-granule LDS reads.

#define PIX 25600
#define CIN 64
#define COUT 64
#define BATCH 32
#define NEXP 8
#define TILE_PX 128
#define TILES_PER_B (PIX / TILE_PX) // 200

__device__ __forceinline__ void load_lds16(const float* g, float* l) {
  // async global->LDS, 16B/lane; global addr per-lane, LDS dst uniform+lane*16
  __builtin_amdgcn_global_load_lds(
      (__attribute__((address_space(1))) void*)(g),
      (__attribute__((address_space(3))) void*)(l), 16, 0, 0);
}

// ---------------- Kernel A: mix kernels, store TRANSPOSED kt[b][i][o] -------
__global__ __launch_bounds__(256) void mix_kernel(
    const float* __restrict__ alpha, const float* __restrict__ ke,
    float* __restrict__ kt) {
  const int b = blockIdx.x >> 3;
  const int seg = blockIdx.x & 7;
  __shared__ float a[NEXP];
  if (threadIdx.x < NEXP) a[threadIdx.x] = alpha[b * NEXP + threadIdx.x];
  __syncthreads();
#pragma unroll
  for (int t = 0; t < 2; t++) {
    const int idx = seg * 512 + t * 256 + threadIdx.x; // idx = o*64 + i
    float s = 0.f;
#pragma unroll
    for (int e = 0; e < NEXP; e++) s += a[e] * ke[e * 4096 + idx];
    const int o = idx >> 6, i = idx & 63;
    kt[b * 4096 + i * 64 + o] = s; // transposed: [i][o]
  }
}

// ---------------- Kernel B: single-stage 1x1-conv GEMM ----------------------
// Block = (sample b) x (128-pixel tile); 256 threads; 6400 blocks.
// LDS: ks[64][64] ([i][o], 16KB) + xs[64 rows][128 px] (32KB) = 48KB -> 3 blk/CU.
// ONE barrier per block: stage everything async, sync once, compute 64 K-steps.
// Thread tile: tc=tid>>5 -> 8 out-channels, tp=tid&31 -> 4 pixels (acc[8][4]).
// xs read: lane tp reads 16B granule tp of a 512B row -> 32 consecutive
// granules/wave = ideal LDS pattern, no bank conflicts. ks reads: 2 distinct
// addresses/wave -> broadcast, free.
__global__ __launch_bounds__(256, 3) void conv_kernel(
    const float* __restrict__ x, const float* __restrict__ kt,
    float* __restrict__ out) {
  __shared__ float ks[CIN * COUT];
  __shared__ float xs[CIN * TILE_PX];

  const int bid = blockIdx.x;
  const int b = bid / TILES_PER_B;
  const int tile = bid - b * TILES_PER_B;
  const int P0 = tile * TILE_PX;

  const int tid = threadIdx.x;
  const int wave = tid >> 6;
  const int lane = tid & 63;
  const int tc = tid >> 5; // 0..7 (channel group of 8)
  const int tp = tid & 31; // 0..31 (pixel group of 4)

  const float* xb = x + (size_t)b * CIN * PIX + P0;
  const float* kb = kt + b * 4096;

  // Stage ks: 16KB = 16 wave-instrs; wave w does 4 (each 256 floats = 4 K-rows)
#pragma unroll
  for (int j = 0; j < 4; j++) {
    const int r = wave * 4 + j;
    load_lds16(kb + r * 256 + lane * 4, &ks[r * 256]);
  }

  // Stage xs: 64 rows x 128 px; wave w stages rows 16w..16w+15, 2 rows/instr
  // (lanes 0-31 -> row r, lanes 32-63 -> row r+1; 512B contiguous per row).
#pragma unroll
  for (int j = 0; j < 8; j++) {
    const int r = wave * 16 + j * 2;
    load_lds16(xb + (size_t)(r + (lane >> 5)) * PIX + (lane & 31) * 4,
               &xs[r * TILE_PX]);
  }

  float acc[8][4];
#pragma unroll
  for (int c = 0; c < 8; c++)
#pragma unroll
    for (int p = 0; p < 4; p++) acc[c][p] = 0.f;

  __syncthreads(); // single barrier: drains vmcnt(0), staged data visible

  const float* xp4 = xs + tp * 4;
  const float* kp = ks + tc * 8;
#pragma unroll 8
  for (int ii = 0; ii < CIN; ii++) {
    const float4 xv = *(const float4*)(xp4 + ii * TILE_PX);
    const float4 k0 = *(const float4*)(kp + ii * 64);
    const float4 k1 = *(const float4*)(kp + ii * 64 + 4);
    const float kc[8] = {k0.x, k0.y, k0.z, k0.w, k1.x, k1.y, k1.z, k1.w};
    const float xv4[4] = {xv.x, xv.y, xv.z, xv.w};
#pragma unroll
    for (int c = 0; c < 8; c++)
#pragma unroll
      for (int p = 0; p < 4; p++) acc[c][p] = fmaf(kc[c], xv4[p], acc[c][p]);
  }

  // Epilogue: 8 x float4 stores; lanes sharing tc cover 512B contiguous.
  float* ob = out + ((size_t)(b * COUT + tc * 8)) * PIX + P0 + tp * 4;
#pragma unroll
  for (int c = 0; c < 8; c++) {
    *(float4*)(ob + (size_t)c * PIX) =
        make_float4(acc[c][0], acc[c][1], acc[c][2], acc[c][3]);
  }
}

extern "C" void kernel_launch(void* const* d_in, const int* in_sizes, int n_in,
                              void* d_out, int out_size, void* d_ws,
                              size_t ws_size, hipStream_t stream) {
  const float* x = (const float*)d_in[0];     // [32,64,160,160]
  const float* alpha = (const float*)d_in[1]; // [32,8]
  const float* ke = (const float*)d_in[2];    // [8,64,64,1,1]
  float* out = (float*)d_out;                 // [32,64,160,160]
  float* kt = (float*)d_ws;                   // 32*4096 floats = 512KB scratch

  mix_kernel<<<BATCH * 8, 256, 0, stream>>>(alpha, ke, kt);
  conv_kernel<<<BATCH * TILES_PER_B, 256, 0, stream>>>(x, kt, out);
}